// Round 1
// baseline (364.776 us; speedup 1.0000x reference)
//
#include <hip/hip_runtime.h>

// VQ codebook lookup (VQ-VAE quantize) on MI355X.
// x: [32,64,64,64] f32 -> N=131072 vectors of DIM=64; embed: [DIM=64, K=512] f32.
// Outputs (flat f32, concatenated): quantize [N*DIM], diff [1], embed_ind [N].

#define DIM   64
#define NCODE 512
#define NVEC  (32 * 64 * 64)   // 131072
#define KT    64               // codes per LDS tile (16 KB)
#define BLK   256

// Transpose embed [DIM][NCODE] -> et [NCODE][DIM], and per-code squared norms.
__global__ void vq_prep(const float* __restrict__ embed,
                        float* __restrict__ et,
                        float* __restrict__ norms) {
    const int k = blockIdx.x * blockDim.x + threadIdx.x;
    if (k >= NCODE) return;
    float s = 0.0f;
    #pragma unroll 8
    for (int d = 0; d < DIM; ++d) {
        const float v = embed[d * NCODE + k];   // coalesced in k
        et[k * DIM + d] = v;
        s = fmaf(v, v, s);
    }
    norms[k] = s;
}

__global__ __launch_bounds__(BLK, 2) void vq_main(
        const float* __restrict__ x,
        const float* __restrict__ et,
        const float* __restrict__ norms,
        float* __restrict__ out) {
    __shared__ float lds_e[KT * DIM];   // 16 KB tile of codes
    __shared__ float lds_n[KT];
    __shared__ float red[BLK / 64];

    const int tid = threadIdx.x;
    const long n = (long)blockIdx.x * BLK + tid;   // vector index (grid exact)

    // x row into registers (fully unrolled, constant indices -> VGPRs)
    float xv[DIM];
    const float* xp = x + n * DIM;
    #pragma unroll
    for (int d = 0; d < DIM; d += 4) {
        const float4 t = *reinterpret_cast<const float4*>(xp + d);
        xv[d + 0] = t.x; xv[d + 1] = t.y; xv[d + 2] = t.z; xv[d + 3] = t.w;
    }

    float best = __builtin_inff();
    int bestk = 0;

    for (int t = 0; t < NCODE / KT; ++t) {
        __syncthreads();
        // cooperative tile load: KT*DIM = 4096 floats, 256 threads x float4 x 4
        const float* src = et + t * (KT * DIM);
        #pragma unroll
        for (int i = 0; i < (KT * DIM) / (BLK * 4); ++i) {
            const int idx = (i * BLK + tid) * 4;
            *reinterpret_cast<float4*>(&lds_e[idx]) =
                *reinterpret_cast<const float4*>(src + idx);
        }
        if (tid < KT) lds_n[tid] = norms[t * KT + tid];
        __syncthreads();

        for (int c = 0; c < KT; ++c) {
            const float* ep = &lds_e[c * DIM];   // uniform addr -> LDS broadcast
            float a0 = 0.f, a1 = 0.f, a2 = 0.f, a3 = 0.f;
            #pragma unroll
            for (int d = 0; d < DIM; d += 4) {
                const float4 e4 = *reinterpret_cast<const float4*>(ep + d);
                a0 = fmaf(xv[d + 0], e4.x, a0);
                a1 = fmaf(xv[d + 1], e4.y, a1);
                a2 = fmaf(xv[d + 2], e4.z, a2);
                a3 = fmaf(xv[d + 3], e4.w, a3);
            }
            const float dot = (a0 + a1) + (a2 + a3);
            // ||x||^2 omitted: constant per row, same argmin
            const float score = fmaf(-2.0f, dot, lds_n[c]);
            if (score < best) { best = score; bestk = t * KT + c; }
        }
    }

    // Epilogue: gather winning code, write quantize (== quantize_st), index, diff.
    float dp = 0.0f;
    const float* qp = et + (long)bestk * DIM;
    float* op = out + n * DIM;
    #pragma unroll
    for (int d = 0; d < DIM; d += 4) {
        const float4 q4 = *reinterpret_cast<const float4*>(qp + d);
        *reinterpret_cast<float4*>(op + d) = q4;
        const float d0 = q4.x - xv[d + 0];
        const float d1 = q4.y - xv[d + 1];
        const float d2 = q4.z - xv[d + 2];
        const float d3 = q4.w - xv[d + 3];
        dp = fmaf(d0, d0, dp);
        dp = fmaf(d1, d1, dp);
        dp = fmaf(d2, d2, dp);
        dp = fmaf(d3, d3, dp);
    }
    out[(long)NVEC * DIM + 1 + n] = (float)bestk;

    // block-reduce dp -> one atomicAdd per block into the diff slot
    #pragma unroll
    for (int off = 32; off >= 1; off >>= 1)
        dp += __shfl_down(dp, off, 64);
    if ((tid & 63) == 0) red[tid >> 6] = dp;
    __syncthreads();
    if (tid == 0) {
        const float s = (red[0] + red[1]) + (red[2] + red[3]);
        atomicAdd(&out[(long)NVEC * DIM],
                  s * (1.0f / ((float)NVEC * (float)DIM)));
    }
}

extern "C" void kernel_launch(void* const* d_in, const int* in_sizes, int n_in,
                              void* d_out, int out_size, void* d_ws, size_t ws_size,
                              hipStream_t stream) {
    const float* x     = (const float*)d_in[0];
    const float* embed = (const float*)d_in[1];
    float* out   = (float*)d_out;
    float* et    = (float*)d_ws;                 // 512*64 f32 = 128 KB
    float* norms = et + (size_t)NCODE * DIM;     // 512 f32

    // zero the diff accumulator slot (d_out is poisoned 0xAA before each call)
    hipMemsetAsync((char*)d_out + (size_t)NVEC * DIM * sizeof(float), 0,
                   sizeof(float), stream);

    vq_prep<<<(NCODE + BLK - 1) / BLK, BLK, 0, stream>>>(embed, et, norms);
    vq_main<<<NVEC / BLK, BLK, 0, stream>>>(x, et, norms, out);
}

// Round 2
// 136.973 us; speedup vs baseline: 2.6631x; 2.6631x over previous
//
#include <hip/hip_runtime.h>

// VQ codebook lookup via MFMA on MI355X (gfx950).
// x: [32,64,64,64] f32 -> N=131072 rows, DIM=64; embed: [64, 512] f32.
// fp32 exactly decomposed into 3 bf16 planes (8+8+8 mantissa bits, truncation);
// dot = 6 cross-products accumulated in fp32 MFMA -> ~1e-6 error (fp32-grade).
// Outputs (flat f32): quantize [N*64], diff [1], embed_ind [N].

#define DIM      64
#define NCODE    512
#define NVEC     (32 * 64 * 64)   // 131072
#define WAVES    4
#define BLK      256
#define NCT      16               // col-tiles of 32 codes
#define CHUNK_DW 3072             // dwords per col-tile chunk (12 KB)

typedef unsigned int u32;
typedef __attribute__((ext_vector_type(8)))  short bf16x8;
typedef __attribute__((ext_vector_type(16))) float f32x16;

#define GLOAD_LDS16(gp, lp)                                                      \
  __builtin_amdgcn_global_load_lds(                                              \
      (const __attribute__((address_space(1))) u32*)(gp),                        \
      (__attribute__((address_space(3))) u32*)(lp), 16, 0, 0)

// Exact 3-plane bf16 split: v == hi + mid + lo (all remainders representable).
__device__ __forceinline__ void split3(float v, u32& h, u32& m, u32& lo) {
    const u32 u = __float_as_uint(v);
    h = u >> 16;
    const float r1 = v - __uint_as_float(u & 0xFFFF0000u);
    const u32 u1 = __float_as_uint(r1);
    m = u1 >> 16;
    const float r2 = r1 - __uint_as_float(u1 & 0xFFFF0000u);
    lo = __float_as_uint(r2) >> 16;
}

// Build B-fragments (3 planes, frag-layout in ws), fp32 et transpose, norms.
// Grid: 4 blocks x 256. Thread tg in [0,1024): frag role (ct = tg>>6, lane = tg&63).
__global__ void vq_prep(const float* __restrict__ embed,
                        u32* __restrict__ bfrag,
                        float* __restrict__ et,
                        float* __restrict__ norms) {
    const int tg = blockIdx.x * BLK + threadIdx.x;
    {   // fragment build: code c = ct*32 + (l&31); k-half = l>>5; dims 16s + kh*8 + j
        const int ct = tg >> 6, l = tg & 63;
        const int c = ct * 32 + (l & 31), kh = l >> 5;
        double nsum = 0.0;
        u32 w[3][4][4];   // [plane][kstep s][dword q]
        #pragma unroll
        for (int s = 0; s < 4; ++s) {
            float v[8];
            #pragma unroll
            for (int j = 0; j < 8; ++j) {
                const int d = 16 * s + kh * 8 + j;
                v[j] = embed[d * NCODE + c];
                nsum += (double)v[j] * (double)v[j];
            }
            #pragma unroll
            for (int q = 0; q < 4; ++q) {
                u32 h0, m0, l0, h1, m1, l1;
                split3(v[2 * q], h0, m0, l0);
                split3(v[2 * q + 1], h1, m1, l1);
                w[0][s][q] = h0 | (h1 << 16);
                w[1][s][q] = m0 | (m1 << 16);
                w[2][s][q] = l0 | (l1 << 16);
            }
        }
        const double tot = nsum + __shfl_xor(nsum, 32, 64);
        if (kh == 0) norms[c] = (float)tot;
        #pragma unroll
        for (int p = 0; p < 3; ++p) {
            #pragma unroll
            for (int s = 0; s < 4; ++s) {
                u32* dst = bfrag + ct * CHUNK_DW + (p * 4 + s) * 256 + l * 4;
                *reinterpret_cast<uint4*>(dst) =
                    make_uint4(w[p][s][0], w[p][s][1], w[p][s][2], w[p][s][3]);
            }
        }
    }
    {   // et transpose: et[c][d] = embed[d][c]
        const int c = tg >> 1, dh = (tg & 1) * 32;
        float buf[32];
        #pragma unroll
        for (int i = 0; i < 32; ++i) buf[i] = embed[(dh + i) * NCODE + c];
        #pragma unroll
        for (int i = 0; i < 8; ++i)
            *reinterpret_cast<float4*>(et + c * DIM + dh + i * 4) =
                make_float4(buf[4 * i], buf[4 * i + 1], buf[4 * i + 2], buf[4 * i + 3]);
    }
}

__global__ __launch_bounds__(BLK, 3) void vq_main(
        const float* __restrict__ x,
        const u32* __restrict__ bfrag,
        const float* __restrict__ et,
        const float* __restrict__ norms,
        float* __restrict__ out) {
    __shared__ u32 lbuf[2][CHUNK_DW];    // double-buffered code-frag tile (2x12 KB)
    __shared__ float lnorm[NCODE];
    __shared__ int sbk[WAVES][32];
    __shared__ float red[WAVES];

    const int tid = threadIdx.x;
    const int wid = tid >> 6, l = tid & 63;
    const int rl = l & 31, kh = l >> 5;
    const int n0 = (blockIdx.x * WAVES + wid) * 32;   // wave's 32 rows

    for (int i = tid; i < NCODE; i += BLK) lnorm[i] = norms[i];

    // ---- A fragments: 32 rows x 64 dims, 3 planes x 4 k-steps, kept in VGPRs ----
    bf16x8 afr[3][4];
    {
        const float* xp = x + (size_t)(n0 + rl) * DIM + kh * 8;
        #pragma unroll
        for (int s = 0; s < 4; ++s) {
            const float4 va = *reinterpret_cast<const float4*>(xp + 16 * s);
            const float4 vb = *reinterpret_cast<const float4*>(xp + 16 * s + 4);
            const float v[8] = {va.x, va.y, va.z, va.w, vb.x, vb.y, vb.z, vb.w};
            #pragma unroll
            for (int q = 0; q < 4; ++q) {
                u32 h0, m0, l0, h1, m1, l1;
                split3(v[2 * q], h0, m0, l0);
                split3(v[2 * q + 1], h1, m1, l1);
                afr[0][s][2 * q] = (short)h0;  afr[0][s][2 * q + 1] = (short)h1;
                afr[1][s][2 * q] = (short)m0;  afr[1][s][2 * q + 1] = (short)m1;
                afr[2][s][2 * q] = (short)l0;  afr[2][s][2 * q + 1] = (short)l1;
            }
        }
    }

    // ---- prologue: stage col-tile 0 ----
    {
        const u32* gsrc = bfrag + wid * 256 + (l << 2);
        u32* lp = &lbuf[0][wid * 256];
        #pragma unroll
        for (int i = 0; i < 3; ++i) GLOAD_LDS16(gsrc + i * 1024, lp + i * 1024);
    }
    __syncthreads();   // drains vmcnt: tile 0 resident; lnorm visible

    float best[16];
    int bk[16];
    #pragma unroll
    for (int r = 0; r < 16; ++r) { best[r] = __builtin_inff(); bk[r] = 0; }

    int cur = 0;
    for (int ct = 0; ct < NCT; ++ct) {
        if (ct + 1 < NCT) {   // stage next tile into the other buffer (flies under compute)
            const u32* gsrc = bfrag + (ct + 1) * CHUNK_DW + wid * 256 + (l << 2);
            u32* lp = &lbuf[cur ^ 1][wid * 256];
            #pragma unroll
            for (int i = 0; i < 3; ++i) GLOAD_LDS16(gsrc + i * 1024, lp + i * 1024);
        }

        f32x16 acc;
        #pragma unroll
        for (int r = 0; r < 16; ++r) acc[r] = 0.0f;

        const int l4 = l << 2;
        #pragma unroll
        for (int s = 0; s < 4; ++s) {
            const bf16x8 bh = *reinterpret_cast<const bf16x8*>(&lbuf[cur][(0 * 4 + s) * 256 + l4]);
            const bf16x8 bm = *reinterpret_cast<const bf16x8*>(&lbuf[cur][(1 * 4 + s) * 256 + l4]);
            const bf16x8 bl = *reinterpret_cast<const bf16x8*>(&lbuf[cur][(2 * 4 + s) * 256 + l4]);
            acc = __builtin_amdgcn_mfma_f32_32x32x16_bf16(afr[0][s], bh, acc, 0, 0, 0);
            acc = __builtin_amdgcn_mfma_f32_32x32x16_bf16(afr[0][s], bm, acc, 0, 0, 0);
            acc = __builtin_amdgcn_mfma_f32_32x32x16_bf16(afr[1][s], bh, acc, 0, 0, 0);
            acc = __builtin_amdgcn_mfma_f32_32x32x16_bf16(afr[1][s], bm, acc, 0, 0, 0);
            acc = __builtin_amdgcn_mfma_f32_32x32x16_bf16(afr[0][s], bl, acc, 0, 0, 0);
            acc = __builtin_amdgcn_mfma_f32_32x32x16_bf16(afr[2][s], bh, acc, 0, 0, 0);
        }

        const int col = ct * 32 + rl;
        const float nrm = lnorm[col];
        #pragma unroll
        for (int r = 0; r < 16; ++r) {
            const float sc = fmaf(-2.0f, acc[r], nrm);   // ||x||^2 constant per row: dropped
            if (sc < best[r]) { best[r] = sc; bk[r] = col; }   // strict < => first index on ties
        }

        __syncthreads();   // all reads of lbuf[cur] done + next tile's loads drained
        cur ^= 1;
    }

    // ---- cross-lane argmin over the 32 columns (lanes sharing kh), np tie-break ----
    #pragma unroll
    for (int off = 1; off <= 16; off <<= 1) {
        #pragma unroll
        for (int r = 0; r < 16; ++r) {
            const float ob = __shfl_xor(best[r], off, 64);
            const int obk  = __shfl_xor(bk[r], off, 64);
            if (ob < best[r] || (ob == best[r] && obk < bk[r])) { best[r] = ob; bk[r] = obk; }
        }
    }
    // C layout (m74/m101): row = (r&3) + 8*(r>>2) + 4*kh, col = lane&31
    if (rl == 0) {
        #pragma unroll
        for (int r = 0; r < 16; ++r) sbk[wid][(r & 3) + 8 * (r >> 2) + 4 * kh] = bk[r];
    }

    // ---- epilogue: coalesced quantize write + diff + indices ----
    float dp = 0.0f;
    const int rsub = l >> 4;            // 0..3
    const int dcol = (l & 15) * 4;      // 0..60
    #pragma unroll
    for (int i = 0; i < 8; ++i) {
        const int row = i * 4 + rsub;
        const int k = sbk[wid][row];
        const float4 q  = *reinterpret_cast<const float4*>(et + k * DIM + dcol);
        const float4 xv = *reinterpret_cast<const float4*>(x + (size_t)(n0 + row) * DIM + dcol);
        *reinterpret_cast<float4*>(out + (size_t)(n0 + row) * DIM + dcol) = q;
        const float d0 = q.x - xv.x, d1 = q.y - xv.y, d2 = q.z - xv.z, d3 = q.w - xv.w;
        dp = fmaf(d0, d0, dp); dp = fmaf(d1, d1, dp);
        dp = fmaf(d2, d2, dp); dp = fmaf(d3, d3, dp);
    }
    if (l < 32) out[(size_t)NVEC * DIM + 1 + n0 + l] = (float)sbk[wid][l];

    #pragma unroll
    for (int off = 32; off >= 1; off >>= 1) dp += __shfl_down(dp, off, 64);
    if (l == 0) red[wid] = dp;
    __syncthreads();
    if (tid == 0) {
        const float s = (red[0] + red[1]) + (red[2] + red[3]);
        atomicAdd(out + (size_t)NVEC * DIM, s * (1.0f / ((float)NVEC * (float)DIM)));
    }
}

extern "C" void kernel_launch(void* const* d_in, const int* in_sizes, int n_in,
                              void* d_out, int out_size, void* d_ws, size_t ws_size,
                              hipStream_t stream) {
    const float* x     = (const float*)d_in[0];
    const float* embed = (const float*)d_in[1];
    float* out = (float*)d_out;

    u32* bfrag   = (u32*)d_ws;                       // 16*3072 dwords = 192 KB
    float* et    = (float*)d_ws + NCT * CHUNK_DW;    // 512*64 f32 = 128 KB
    float* norms = et + (size_t)NCODE * DIM;         // 512 f32

    // zero the diff accumulator slot (d_out is poisoned 0xAA before each call)
    hipMemsetAsync((char*)d_out + (size_t)NVEC * DIM * sizeof(float), 0,
                   sizeof(float), stream);

    vq_prep<<<4, BLK, 0, stream>>>(embed, bfrag, et, norms);
    vq_main<<<NVEC / (WAVES * 32), BLK, 0, stream>>>(x, bfrag, et, norms, out);
}

// Round 3
// 134.436 us; speedup vs baseline: 2.7134x; 1.0189x over previous
//
#include <hip/hip_runtime.h>

// VQ codebook lookup via MFMA on MI355X (gfx950).
// x: [32,64,64,64] f32 -> N=131072 rows, DIM=64; embed: [64, 512] f32.
// fp32 exactly decomposed into 3 bf16 planes (8+8+8 mantissa bits, truncation);
// dot = 6 cross-products accumulated in fp32 MFMA -> ~1e-6 error (fp32-grade).
// Outputs (flat f32): quantize [N*64], diff [1], embed_ind [N].
//
// R2 changes: (1) vq_prep 4 -> 16 blocks, one thread per (code, 8-dim chunk),
// diff-slot zeroing folded in (memset node dropped). (2) vq_main: counted
// s_waitcnt vmcnt(3) + raw s_barrier pipeline (T3+T4) instead of the
// __syncthreads full-drain; launch_bounds(256,4) for 4 blocks/CU.

#define DIM      64
#define NCODE    512
#define NVEC     (32 * 64 * 64)   // 131072
#define WAVES    4
#define BLK      256
#define NCT      16               // col-tiles of 32 codes
#define CHUNK_DW 3072             // dwords per col-tile chunk (12 KB)

typedef unsigned int u32;
typedef __attribute__((ext_vector_type(8)))  short bf16x8;
typedef __attribute__((ext_vector_type(16))) float f32x16;

#define GLOAD_LDS16(gp, lp)                                                      \
  __builtin_amdgcn_global_load_lds(                                              \
      (const __attribute__((address_space(1))) u32*)(gp),                        \
      (__attribute__((address_space(3))) u32*)(lp), 16, 0, 0)

// Exact 3-plane bf16 split: v == hi + mid + lo (24 mantissa bits in 3x8).
__device__ __forceinline__ void split3(float v, u32& h, u32& m, u32& lo) {
    const u32 u = __float_as_uint(v);
    h = u >> 16;
    const float r1 = v - __uint_as_float(u & 0xFFFF0000u);
    const u32 u1 = __float_as_uint(r1);
    m = u1 >> 16;
    const float r2 = r1 - __uint_as_float(u1 & 0xFFFF0000u);
    lo = __float_as_uint(r2) >> 16;
}

// 16 blocks x 256 = 4096 threads: thread = (code c, 8-dim chunk g).
// Builds B-fragments (3 planes, MFMA frag layout), et transpose, f64 norms,
// and zeroes the diff output slot.
__global__ void vq_prep(const float* __restrict__ embed,
                        u32* __restrict__ bfrag,
                        float* __restrict__ et,
                        float* __restrict__ norms,
                        float* __restrict__ out) {
    const int gid = blockIdx.x * BLK + threadIdx.x;   // [0, 4096)
    const int c = gid >> 3, g = gid & 7;
    const int s = g >> 1, kh = g & 1;                 // dims 16s + 8kh + j

    float v[8];
    double ns = 0.0;
    #pragma unroll
    for (int j = 0; j < 8; ++j) {
        v[j] = embed[(16 * s + 8 * kh + j) * NCODE + c];
        ns += (double)v[j] * (double)v[j];
    }
    // reduce squared norm across the 8 threads sharing code c (same wave)
    ns += __shfl_xor(ns, 1, 64);
    ns += __shfl_xor(ns, 2, 64);
    ns += __shfl_xor(ns, 4, 64);
    if (g == 0) norms[c] = (float)ns;

    u32 wH[4], wM[4], wL[4];
    #pragma unroll
    for (int q = 0; q < 4; ++q) {
        u32 h0, m0, l0, h1, m1, l1;
        split3(v[2 * q], h0, m0, l0);
        split3(v[2 * q + 1], h1, m1, l1);
        wH[q] = h0 | (h1 << 16);
        wM[q] = m0 | (m1 << 16);
        wL[q] = l0 | (l1 << 16);
    }
    const int ct = c >> 5, lb = (c & 31) + 32 * kh;
    u32* base = bfrag + ct * CHUNK_DW;
    *reinterpret_cast<uint4*>(base + (0 * 4 + s) * 256 + lb * 4) =
        make_uint4(wH[0], wH[1], wH[2], wH[3]);
    *reinterpret_cast<uint4*>(base + (1 * 4 + s) * 256 + lb * 4) =
        make_uint4(wM[0], wM[1], wM[2], wM[3]);
    *reinterpret_cast<uint4*>(base + (2 * 4 + s) * 256 + lb * 4) =
        make_uint4(wL[0], wL[1], wL[2], wL[3]);

    // et transpose: et[c][d] = embed[d][c] for this thread's 8 dims
    float* ep = et + c * DIM + 16 * s + 8 * kh;
    *reinterpret_cast<float4*>(ep)     = make_float4(v[0], v[1], v[2], v[3]);
    *reinterpret_cast<float4*>(ep + 4) = make_float4(v[4], v[5], v[6], v[7]);

    if (gid == 0) out[(size_t)NVEC * DIM] = 0.0f;   // diff accumulator slot
}

__global__ __launch_bounds__(BLK, 4) void vq_main(
        const float* __restrict__ x,
        const u32* __restrict__ bfrag,
        const float* __restrict__ et,
        const float* __restrict__ norms,
        float* __restrict__ out) {
    __shared__ __align__(16) u32 lbuf[2][CHUNK_DW];   // double-buffered tile (2x12 KB)
    __shared__ float lnorm[NCODE];
    __shared__ int sbk[WAVES][32];
    __shared__ float red[WAVES];

    const int tid = threadIdx.x;
    const int wid = tid >> 6, l = tid & 63;
    const int rl = l & 31, kh = l >> 5;
    const int n0 = (blockIdx.x * WAVES + wid) * 32;   // wave's 32 rows

    // ---- issue tile-0 staging first; its latency hides under A-frag build ----
    {
        const u32* gsrc = bfrag + wid * 256 + (l << 2);
        u32* lp = &lbuf[0][wid * 256];
        GLOAD_LDS16(gsrc, lp);
        GLOAD_LDS16(gsrc + 1024, lp + 1024);
        GLOAD_LDS16(gsrc + 2048, lp + 2048);
    }
    for (int i = tid; i < NCODE; i += BLK) lnorm[i] = norms[i];

    // ---- A fragments: 32 rows x 64 dims, 3 planes x 4 k-steps, in VGPRs ----
    bf16x8 afr[3][4];
    {
        const float* xp = x + (size_t)(n0 + rl) * DIM + kh * 8;
        #pragma unroll
        for (int s = 0; s < 4; ++s) {
            const float4 va = *reinterpret_cast<const float4*>(xp + 16 * s);
            const float4 vb = *reinterpret_cast<const float4*>(xp + 16 * s + 4);
            const float v[8] = {va.x, va.y, va.z, va.w, vb.x, vb.y, vb.z, vb.w};
            #pragma unroll
            for (int q = 0; q < 4; ++q) {
                u32 h0, m0, l0, h1, m1, l1;
                split3(v[2 * q], h0, m0, l0);
                split3(v[2 * q + 1], h1, m1, l1);
                afr[0][s][2 * q] = (short)h0;  afr[0][s][2 * q + 1] = (short)h1;
                afr[1][s][2 * q] = (short)m0;  afr[1][s][2 * q + 1] = (short)m1;
                afr[2][s][2 * q] = (short)l0;  afr[2][s][2 * q + 1] = (short)l1;
            }
        }
    }

    float best[16];
    int bk[16];
    #pragma unroll
    for (int r = 0; r < 16; ++r) { best[r] = __builtin_inff(); bk[r] = 0; }

    // ---- main loop: counted-vmcnt pipeline, 2 raw barriers per tile ----
    // iter ct: [issue t_{ct+1}] [vmcnt(3): own t_ct landed] [bar1: all waves'
    // t_ct chunks visible] [compute t_ct] [bar2: safe to overwrite buf^1 next]
    for (int ct = 0; ct < NCT; ++ct) {
        const int cur = ct & 1;
        if (ct + 1 < NCT) {
            const u32* gsrc = bfrag + (ct + 1) * CHUNK_DW + wid * 256 + (l << 2);
            u32* lp = &lbuf[cur ^ 1][wid * 256];
            GLOAD_LDS16(gsrc, lp);
            GLOAD_LDS16(gsrc + 1024, lp + 1024);
            GLOAD_LDS16(gsrc + 2048, lp + 2048);
            asm volatile("s_waitcnt vmcnt(3)" ::: "memory");
        } else {
            asm volatile("s_waitcnt vmcnt(0)" ::: "memory");
        }
        asm volatile("s_barrier" ::: "memory");

        f32x16 acc;
        #pragma unroll
        for (int r = 0; r < 16; ++r) acc[r] = 0.0f;

        const int l4 = l << 2;
        #pragma unroll
        for (int s = 0; s < 4; ++s) {
            const bf16x8 bh = *reinterpret_cast<const bf16x8*>(&lbuf[cur][(0 * 4 + s) * 256 + l4]);
            const bf16x8 bm = *reinterpret_cast<const bf16x8*>(&lbuf[cur][(1 * 4 + s) * 256 + l4]);
            const bf16x8 bl = *reinterpret_cast<const bf16x8*>(&lbuf[cur][(2 * 4 + s) * 256 + l4]);
            acc = __builtin_amdgcn_mfma_f32_32x32x16_bf16(afr[0][s], bh, acc, 0, 0, 0);
            acc = __builtin_amdgcn_mfma_f32_32x32x16_bf16(afr[0][s], bm, acc, 0, 0, 0);
            acc = __builtin_amdgcn_mfma_f32_32x32x16_bf16(afr[1][s], bh, acc, 0, 0, 0);
            acc = __builtin_amdgcn_mfma_f32_32x32x16_bf16(afr[1][s], bm, acc, 0, 0, 0);
            acc = __builtin_amdgcn_mfma_f32_32x32x16_bf16(afr[0][s], bl, acc, 0, 0, 0);
            acc = __builtin_amdgcn_mfma_f32_32x32x16_bf16(afr[2][s], bh, acc, 0, 0, 0);
        }

        const int col = ct * 32 + rl;
        const float nrm = lnorm[col];
        #pragma unroll
        for (int r = 0; r < 16; ++r) {
            const float sc = fmaf(-2.0f, acc[r], nrm);   // ||x||^2 constant per row: dropped
            if (sc < best[r]) { best[r] = sc; bk[r] = col; }   // strict < => first index on ties
        }

        asm volatile("s_barrier" ::: "memory");
    }

    // ---- cross-lane argmin over the 32 columns (lanes sharing kh), np tie-break ----
    #pragma unroll
    for (int off = 1; off <= 16; off <<= 1) {
        #pragma unroll
        for (int r = 0; r < 16; ++r) {
            const float ob = __shfl_xor(best[r], off, 64);
            const int obk  = __shfl_xor(bk[r], off, 64);
            if (ob < best[r] || (ob == best[r] && obk < bk[r])) { best[r] = ob; bk[r] = obk; }
        }
    }
    // C layout (m74/m101): row = (r&3) + 8*(r>>2) + 4*kh, col = lane&31
    if (rl == 0) {
        #pragma unroll
        for (int r = 0; r < 16; ++r) sbk[wid][(r & 3) + 8 * (r >> 2) + 4 * kh] = bk[r];
    }

    // ---- epilogue: coalesced quantize write + diff + indices ----
    float dp = 0.0f;
    const int rsub = l >> 4;            // 0..3
    const int dcol = (l & 15) * 4;      // 0..60
    #pragma unroll
    for (int i = 0; i < 8; ++i) {
        const int row = i * 4 + rsub;
        const int k = sbk[wid][row];
        const float4 q  = *reinterpret_cast<const float4*>(et + k * DIM + dcol);
        const float4 xv = *reinterpret_cast<const float4*>(x + (size_t)(n0 + row) * DIM + dcol);
        *reinterpret_cast<float4*>(out + (size_t)(n0 + row) * DIM + dcol) = q;
        const float d0 = q.x - xv.x, d1 = q.y - xv.y, d2 = q.z - xv.z, d3 = q.w - xv.w;
        dp = fmaf(d0, d0, dp); dp = fmaf(d1, d1, dp);
        dp = fmaf(d2, d2, dp); dp = fmaf(d3, d3, dp);
    }
    if (l < 32) out[(size_t)NVEC * DIM + 1 + n0 + l] = (float)sbk[wid][l];

    #pragma unroll
    for (int off = 32; off >= 1; off >>= 1) dp += __shfl_down(dp, off, 64);
    if (l == 0) red[wid] = dp;
    __syncthreads();
    if (tid == 0) {
        const float s = (red[0] + red[1]) + (red[2] + red[3]);
        atomicAdd(out + (size_t)NVEC * DIM, s * (1.0f / ((float)NVEC * (float)DIM)));
    }
}

extern "C" void kernel_launch(void* const* d_in, const int* in_sizes, int n_in,
                              void* d_out, int out_size, void* d_ws, size_t ws_size,
                              hipStream_t stream) {
    const float* x     = (const float*)d_in[0];
    const float* embed = (const float*)d_in[1];
    float* out = (float*)d_out;

    u32* bfrag   = (u32*)d_ws;                       // 16*3072 dwords = 192 KB
    float* et    = (float*)d_ws + NCT * CHUNK_DW;    // 512*64 f32 = 128 KB
    float* norms = et + (size_t)NCODE * DIM;         // 512 f32

    vq_prep<<<16, BLK, 0, stream>>>(embed, bfrag, et, norms, out);
    vq_main<<<NVEC / (WAVES * 32), BLK, 0, stream>>>(x, bfrag, et, norms, out);
}